// Round 14
// baseline (713.723 us; speedup 1.0000x reference)
//
#include <hip/hip_runtime.h>
#include <hip/hip_bf16.h>

#define HW 65536
#define IMG 256
static constexpr int CDIM = 192;

typedef __attribute__((ext_vector_type(8))) short short8;
typedef __attribute__((ext_vector_type(4))) short s16x4;
typedef __attribute__((ext_vector_type(4))) float f32x4;
typedef __attribute__((ext_vector_type(2))) float f32x2;

static __device__ __forceinline__ float b2f(unsigned short u) {
    union { unsigned u; float f; } t; t.u = ((unsigned)u) << 16; return t.f;
}
static __device__ __forceinline__ unsigned short f2bu(float f) {
    __hip_bfloat16 h = __float2bfloat16(f);
    return *reinterpret_cast<unsigned short*>(&h);
}

// ---------------- pack weights fp32 -> bf16 ---------------------------------
__global__ void pack_weights(const float* __restrict__ wq,
                             const float* __restrict__ wkv,
                             const float* __restrict__ wp,
                             __hip_bfloat16* __restrict__ Wqkv,
                             __hip_bfloat16* __restrict__ Wp) {
    int i = blockIdx.x * 256 + threadIdx.x;
    if (i < 36864) Wqkv[i] = __float2bfloat16(wq[i]);
    else if (i < 110592) Wqkv[i] = __float2bfloat16(wkv[i - 36864]);
    else if (i < 147456) Wp[i - 110592] = __float2bfloat16(wp[i - 110592]);
}

// ---------------- transpose + convert: x[c][p] f32 -> xT[p][c] bf16 ---------
__global__ void transpose_cvt(const float* __restrict__ x,
                              __hip_bfloat16* __restrict__ xT) {
    __shared__ float tile[32][33];
    const int p0 = blockIdx.x * 32, c0 = blockIdx.y * 32;
    const int tx = threadIdx.x & 31, ty = threadIdx.x >> 5;
#pragma unroll
    for (int r = 0; r < 4; r++)
        tile[ty + r * 8][tx] = x[(size_t)(c0 + ty + r * 8) * HW + p0 + tx];
    __syncthreads();
    const int pl = threadIdx.x >> 3, cl = (threadIdx.x & 7) * 4;
    union { unsigned short h[4]; unsigned long long u; } ob;
#pragma unroll
    for (int e = 0; e < 4; e++) ob.h[e] = f2bu(tile[cl + e][pl]);
    *(unsigned long long*)(xT + (size_t)(p0 + pl) * 192 + c0 + cl) = ob.u;
}

// ---------------- MFMA GEMM, BN=64 (6 blocks/CU): Y = A * Bt^T, bf16 out ----
__global__ void gemm_bf16(const __hip_bfloat16* __restrict__ A,
                          const __hip_bfloat16* __restrict__ Bt,
                          __hip_bfloat16* __restrict__ Y) {
    __shared__ short Bs[64][200];
    const int tid = threadIdx.x;
    const int wid = tid >> 6, lane = tid & 63;
    const int mBase = blockIdx.x * 64, nBase = blockIdx.y * 64;

#pragma unroll
    for (int l = 0; l < 6; l++) {
        int ch = tid + l * 256;
        int row = ch / 24, cc = ch % 24;
        short8 v = *(const short8*)(Bt + (size_t)(nBase + row) * 192 + cc * 8);
        *(short8*)&Bs[row][cc * 8] = v;
    }
    __syncthreads();

    const int lr = lane & 15, lg = lane >> 4;
    const __hip_bfloat16* Ab = A + (size_t)(mBase + wid * 16 + lr) * 192 + lg * 8;
    f32x4 acc[4];
#pragma unroll
    for (int f = 0; f < 4; f++) acc[f] = (f32x4){0.f, 0.f, 0.f, 0.f};

#pragma unroll
    for (int ks = 0; ks < 6; ks++) {
        short8 af = *(const short8*)(Ab + ks * 32);
#pragma unroll
        for (int f = 0; f < 4; f++) {
            short8 bfr = *(const short8*)&Bs[f * 16 + lr][ks * 32 + lg * 8];
            acc[f] = __builtin_amdgcn_mfma_f32_16x16x32_bf16(af, bfr, acc[f], 0, 0, 0);
        }
    }

    const int mrow = mBase + wid * 16 + lg * 4;
#pragma unroll
    for (int f = 0; f < 4; f++) {
        int n = nBase + f * 16 + lr;
#pragma unroll
        for (int r = 0; r < 4; r++)
            Y[(size_t)(mrow + r) * HW + n] = __float2bfloat16(acc[f][r]);
    }
}

// ---------------- Depthwise 7x7 v5: bf16 LDS, f32x2 packed accumulate -------
__global__ __launch_bounds__(256) void dwconv7_v5(
    const __hip_bfloat16* __restrict__ in,
    const float* __restrict__ wdw,
    const float* __restrict__ bias,
    __hip_bfloat16* __restrict__ out) {
    __shared__ unsigned short tile[70][136];   // 19,040 B
    const int c = blockIdx.y;
    const int x0 = (blockIdx.x & 1) * 128;
    const int y0 = (blockIdx.x >> 1) * 64;
    const __hip_bfloat16* src = in + (size_t)c * HW;

    float w49[49];
#pragma unroll
    for (int i = 0; i < 49; i++) w49[i] = wdw[c * 49 + i];   // uniform -> SGPR
    const float bval = bias[c];

#pragma unroll
    for (int l = 0; l < 5; l++) {
        int idx = threadIdx.x + l * 256;
        if (idx < 70 * 17) {
            int r = idx / 17, cs = idx - r * 17;
            int gy = y0 + r - 3;
            int gxb = x0 + cs * 8 - 3;
            if ((unsigned)gy < IMG && gxb >= 0 && gxb + 8 <= IMG) {
                *(short8*)&tile[r][cs * 8] =
                    *(const short8*)(src + gy * IMG + gxb);
            } else {
#pragma unroll
                for (int e = 0; e < 8; e++) {
                    int gx = gxb + e;
                    unsigned short val = 0;
                    if ((unsigned)gy < IMG && (unsigned)gx < IMG)
                        val = *(const unsigned short*)(src + gy * IMG + gx);
                    tile[r][cs * 8 + e] = val;
                }
            }
        }
    }
    __syncthreads();

    const int tx4 = (threadIdx.x & 31) * 4;
    const int gy8 = (threadIdx.x >> 5) * 8;
    f32x2 acc2[8][2];
#pragma unroll
    for (int j = 0; j < 8; j++) {
        acc2[j][0] = (f32x2){bval, bval};
        acc2[j][1] = (f32x2){bval, bval};
    }

#pragma unroll
    for (int rr = 0; rr < 14; rr++) {
        const unsigned short* rowp = &tile[gy8 + rr][tx4];
        s16x4 a0 = *(const s16x4*)(rowp);
        s16x4 a1 = *(const s16x4*)(rowp + 4);
        s16x4 a2 = *(const s16x4*)(rowp + 8);
        float win[12];
#pragma unroll
        for (int e = 0; e < 4; e++) {
            win[e]     = b2f((unsigned short)a0[e]);
            win[e + 4] = b2f((unsigned short)a1[e]);
            win[e + 8] = b2f((unsigned short)a2[e]);
        }
#pragma unroll
        for (int j = 0; j < 8; j++) {
            const int ky = rr - j;
            if (ky >= 0 && ky < 7) {
#pragma unroll
                for (int kx = 0; kx < 7; kx++) {
                    const float w = w49[ky * 7 + kx];
                    const f32x2 wv = (f32x2){w, w};
                    acc2[j][0] += (f32x2){win[kx], win[kx + 1]} * wv;
                    acc2[j][1] += (f32x2){win[kx + 2], win[kx + 3]} * wv;
                }
            }
        }
    }

    __hip_bfloat16* dst = out + (size_t)c * HW + (size_t)(y0 + gy8) * IMG + x0 + tx4;
#pragma unroll
    for (int j = 0; j < 8; j++) {
        union { unsigned short h[4]; unsigned long long u; } ob;
        ob.h[0] = f2bu(acc2[j][0][0]);
        ob.h[1] = f2bu(acc2[j][0][1]);
        ob.h[2] = f2bu(acc2[j][1][0]);
        ob.h[3] = f2bu(acc2[j][1][1]);
        *(unsigned long long*)(dst + (size_t)j * IMG) = ob.u;
    }
}

// ------------- Fused dw3x3(q) + per-patch 8x8 circular conv (v4) ------------
// bf16 LDS for qs (raw input copy, lossless) and kP (raw k copy, lossless);
// qP stays f32 (true dw output). LDS 28 -> 18.8 KB -> 7-8 blocks/CU.
// cvt moved to compute. Math bit-identical to v3.
__global__ __launch_bounds__(256) void circ_qfused(
    const __hip_bfloat16* __restrict__ q0,    // pre-dw q (gemm out)
    const __hip_bfloat16* __restrict__ kbuf,  // post-dw k
    const float* __restrict__ w_qdw, const float* __restrict__ b_qdw,
    __hip_bfloat16* __restrict__ sout) {
    __shared__ unsigned short qs[10][272];    // 5,440 B; core at lx = gx+8
    __shared__ float qP[32][68];              // 8,704 B
    __shared__ unsigned short kP[32][72];     // 4,608 B; row 144 B (16B mult)
    const int c = blockIdx.y, ph = blockIdx.x;
    const int y0 = ph * 8;
    const __hip_bfloat16* qsrc = q0 + (size_t)c * HW;
    const __hip_bfloat16* ksrc = kbuf + (size_t)c * HW;

    // q halo rows gy = y0-1..y0+8 at lx = gx+8; raw short8 copy, no cvt.
    for (int t = threadIdx.x; t < 340; t += 256) {
        if (t < 320) {
            int r = t >> 5, ch = t & 31;
            int gy = y0 + r - 1;
            short8 v = (short8){0, 0, 0, 0, 0, 0, 0, 0};
            if ((unsigned)gy < IMG)
                v = *(const short8*)(qsrc + gy * IMG + ch * 8);
            *(short8*)&qs[r][8 + ch * 8] = v;
        } else {
            int e = t - 320;
            int r = e >> 1, s = e & 1;
            qs[r][s ? 264 : 7] = 0;          // gx = 256 / gx = -1 edges
        }
    }
    // k staging: raw short8 copy into patch-major kP
    {
        int a = threadIdx.x >> 5, ch = threadIdx.x & 31;
        short8 v = *(const short8*)(ksrc + (y0 + a) * IMG + ch * 8);
        *(short8*)&kP[ch][a * 8] = v;
    }
    __syncthreads();

    // dw-q 3x3 from bf16 LDS (cvt on read), vertical window -> qP (f32)
    {
        const int x = threadIdx.x;
        float w9[9];
#pragma unroll
        for (int i = 0; i < 9; i++) w9[i] = w_qdw[c * 9 + i];
        float accq[8];
#pragma unroll
        for (int j = 0; j < 8; j++) accq[j] = b_qdw[c];
#pragma unroll
        for (int kx = 0; kx < 3; kx++)
#pragma unroll
            for (int yy = 0; yy < 10; yy++) {
                float vv = b2f(qs[yy][x + kx + 7]);
#pragma unroll
                for (int j = 0; j < 8; j++) {
                    int ky = yy - j;
                    if (ky >= 0 && ky < 3) accq[j] += vv * w9[ky * 3 + kx];
                }
            }
#pragma unroll
        for (int j = 0; j < 8; j++) qP[x >> 3][j * 8 + (x & 7)] = accq[j];
    }
    __syncthreads();

    const int i = threadIdx.x >> 5, pw = threadIdx.x & 31;
    float qv[8][8];
#pragma unroll
    for (int a = 0; a < 8; a++) {
        f32x4 u0 = *(const f32x4*)&qP[pw][a * 8];
        f32x4 u1 = *(const f32x4*)&qP[pw][a * 8 + 4];
        qv[a][0] = u0[0]; qv[a][1] = u0[1]; qv[a][2] = u0[2]; qv[a][3] = u0[3];
        qv[a][4] = u1[0]; qv[a][5] = u1[1]; qv[a][6] = u1[2]; qv[a][7] = u1[3];
    }
    f32x2 acc2[4];
#pragma unroll
    for (int j2 = 0; j2 < 4; j2++) acc2[j2] = (f32x2){0.f, 0.f};

#pragma unroll
    for (int a = 0; a < 8; a++) {
        const int r = (i - a + 8) & 7;
        s16x4 kh0 = *(const s16x4*)&kP[pw][r * 8];
        s16x4 kh1 = *(const s16x4*)&kP[pw][r * 8 + 4];
        const float kr[8] = {
            b2f((unsigned short)kh0[0]), b2f((unsigned short)kh0[1]),
            b2f((unsigned short)kh0[2]), b2f((unsigned short)kh0[3]),
            b2f((unsigned short)kh1[0]), b2f((unsigned short)kh1[1]),
            b2f((unsigned short)kh1[2]), b2f((unsigned short)kh1[3])};
        const f32x2 krE[4] = {(f32x2){kr[0], kr[1]}, (f32x2){kr[2], kr[3]},
                              (f32x2){kr[4], kr[5]}, (f32x2){kr[6], kr[7]}};
        const f32x2 krS[4] = {(f32x2){kr[1], kr[2]}, (f32x2){kr[3], kr[4]},
                              (f32x2){kr[5], kr[6]}, (f32x2){kr[7], kr[0]}};
#pragma unroll
        for (int b = 0; b < 8; b += 2) {
            const float qe = qv[a][b];
            const float qo = qv[a][b + 1];
#pragma unroll
            for (int j2 = 0; j2 < 4; j2++) {
                const int re = (2 * j2 - b + 8) & 7;
                acc2[j2] += (f32x2){qe, qe} * krE[re >> 1];
                const int ro = (2 * j2 - b - 1 + 16) & 7;
                acc2[j2] += (f32x2){qo, qo} * krS[(ro - 1) >> 1];
            }
        }
    }
    union { unsigned short h[8]; short8 s8; } ob;
#pragma unroll
    for (int j = 0; j < 8; j++) ob.h[j] = f2bu(acc2[j >> 1][j & 1]);
    *(short8*)(sout + (size_t)c * HW + (size_t)(y0 + i) * IMG + pw * 8) = ob.s8;
}

// ------------- Fused: LN(ch)+affine, *v, proj GEMM + bias (px-tile 64) ------
// LDS ~28 KB -> 5 blocks/CU (was 54 KB / 2). Stats split 4-way over channels.
__global__ __launch_bounds__(256) void gemm_proj_ln(
    const __hip_bfloat16* __restrict__ Wp,
    const __hip_bfloat16* __restrict__ s,
    const __hip_bfloat16* __restrict__ v,
    const float* __restrict__ ln_w, const float* __restrict__ ln_b,
    const float* __restrict__ bias,
    float* __restrict__ Y) {
    __shared__ short Bs[64][200];
    __shared__ float red[4][2][64];
    __shared__ float muA[64], rsA[64];
    const int tid = threadIdx.x;
    const int p0 = blockIdx.x * 64;
    const int px = tid & 63, h = tid >> 6;
    const unsigned short* sp = (const unsigned short*)s;

    float sum = 0.f, sq = 0.f;
#pragma unroll 4
    for (int l = 0; l < 24; l++) {
        int c = h * 48 + l * 2;
        unsigned short ua = sp[(size_t)c * HW + p0 + px];
        unsigned short ub = sp[(size_t)(c + 1) * HW + p0 + px];
        float a = b2f(ua), b = b2f(ub);
        sum += a + b;
        sq += a * a + b * b;
        *(unsigned*)&Bs[px][c] = (unsigned)ua | ((unsigned)ub << 16);
    }
    red[h][0][px] = sum;
    red[h][1][px] = sq;
    __syncthreads();
    if (tid < 64) {
        float sm = red[0][0][tid] + red[1][0][tid] + red[2][0][tid] + red[3][0][tid];
        float sQ = red[0][1][tid] + red[1][1][tid] + red[2][1][tid] + red[3][1][tid];
        float mu = sm * (1.f / 192.f);
        float var = sQ * (1.f / 192.f) - mu * mu;
        muA[tid] = mu;
        rsA[tid] = rsqrtf(var + 1e-5f);
    }
    __syncthreads();

    const float mu = muA[px], rs = rsA[px];
#pragma unroll 4
    for (int l = 0; l < 24; l++) {
        int c = h * 48 + l * 2;
        unsigned pr = *(unsigned*)&Bs[px][c];
        float a = b2f((unsigned short)pr);
        float b = b2f((unsigned short)(pr >> 16));
        float va = b2f(*(const unsigned short*)(v + (size_t)c * HW + p0 + px));
        float vb = b2f(*(const unsigned short*)(v + (size_t)(c + 1) * HW + p0 + px));
        a = ((a - mu) * rs * ln_w[c] + ln_b[c]) * va;
        b = ((b - mu) * rs * ln_w[c + 1] + ln_b[c + 1]) * vb;
        *(unsigned*)&Bs[px][c] = (unsigned)f2bu(a) | ((unsigned)f2bu(b) << 16);
    }
    __syncthreads();

    const int wid = tid >> 6, lane = tid & 63;
    const int lr = lane & 15, lg = lane >> 4;
    f32x4 acc[3][4];
#pragma unroll
    for (int mf = 0; mf < 3; mf++)
#pragma unroll
        for (int f = 0; f < 4; f++) acc[mf][f] = (f32x4){0.f, 0.f, 0.f, 0.f};

#pragma unroll
    for (int ks = 0; ks < 6; ks++) {
        short8 bfr[4];
#pragma unroll
        for (int f = 0; f < 4; f++)
            bfr[f] = *(const short8*)&Bs[f * 16 + lr][ks * 32 + lg * 8];
#pragma unroll
        for (int mf = 0; mf < 3; mf++) {
            int mrow = wid * 48 + mf * 16 + lr;
            short8 af = *(const short8*)(Wp + (size_t)mrow * 192 + ks * 32 + lg * 8);
#pragma unroll
            for (int f = 0; f < 4; f++)
                acc[mf][f] = __builtin_amdgcn_mfma_f32_16x16x32_bf16(af, bfr[f], acc[mf][f], 0, 0, 0);
        }
    }

#pragma unroll
    for (int mf = 0; mf < 3; mf++) {
        int m0 = wid * 48 + mf * 16 + lg * 4;
#pragma unroll
        for (int f = 0; f < 4; f++) {
            int n = p0 + f * 16 + lr;
#pragma unroll
            for (int r = 0; r < 4; r++)
                Y[(size_t)(m0 + r) * HW + n] = acc[mf][f][r] + bias[m0 + r];
        }
    }
}

extern "C" void kernel_launch(void* const* d_in, const int* in_sizes, int n_in,
                              void* d_out, int out_size, void* d_ws, size_t ws_size,
                              hipStream_t stream) {
    const float* x      = (const float*)d_in[0];
    const float* wq     = (const float*)d_in[1];
    const float* w_qdw  = (const float*)d_in[2];
    const float* b_qdw  = (const float*)d_in[3];
    const float* wkv    = (const float*)d_in[4];
    const float* w_kvdw = (const float*)d_in[5];
    const float* b_kvdw = (const float*)d_in[6];
    const float* ln_w   = (const float*)d_in[7];
    const float* ln_b   = (const float*)d_in[8];
    const float* w_proj = (const float*)d_in[9];
    const float* b_proj = (const float*)d_in[10];
    float* out = (float*)d_out;
    char* ws = (char*)d_ws;

    // ws map (bytes), ~176.5 MB — round-9 proven layout.
    __hip_bfloat16* qkv0  = (__hip_bfloat16*)(ws + 0);           // [576*HW]
    __hip_bfloat16* kvbuf = (__hip_bfloat16*)(ws + 75497472ull); // [384*HW] k|v
    __hip_bfloat16* sbuf  = (__hip_bfloat16*)(ws + 125829120ull);// [192*HW]
    __hip_bfloat16* xT    = (__hip_bfloat16*)(ws + 150994944ull);// [HW*192]
    __hip_bfloat16* Wqkv  = (__hip_bfloat16*)(ws + 176160768ull);// [576*192]
    __hip_bfloat16* Wp    = Wqkv + 110592;                       // [192*192]

    pack_weights<<<576, 256, 0, stream>>>(wq, wkv, w_proj, Wqkv, Wp);

    for (int b = 0; b < 4; b++) {
        const float* xb = x + (size_t)b * CDIM * HW;
        transpose_cvt<<<dim3(HW / 32, 6), 256, 0, stream>>>(xb, xT);
        // fused q+kv 1x1 conv -> bf16 (q rows 0..191, k 192..383, v 384..575)
        gemm_bf16<<<dim3(9, HW / 64), 256, 0, stream>>>(Wqkv, xT, qkv0);
        // depthwise 7x7 over k AND v (384 ch), packed-f32 v5
        dwconv7_v5<<<dim3(8, 384), 256, 0, stream>>>(qkv0 + (size_t)192 * HW,
                                                     w_kvdw, b_kvdw, kvbuf);
        // fused dw3x3(q) + per-patch circular conv (bf16-LDS v4) -> sbuf
        circ_qfused<<<dim3(32, 192), 256, 0, stream>>>(qkv0, kvbuf,
                                                       w_qdw, b_qdw, sbuf);
        // fused LN + *v + projection GEMM + bias (px-64) -> out
        gemm_proj_ln<<<HW / 64, 256, 0, stream>>>(Wp, sbuf,
                                                  kvbuf + (size_t)192 * HW,
                                                  ln_w, ln_b, b_proj,
                                                  out + (size_t)b * CDIM * HW);
    }
}

// Round 15
// 699.319 us; speedup vs baseline: 1.0206x; 1.0206x over previous
//
#include <hip/hip_runtime.h>
#include <hip/hip_bf16.h>

#define HW 65536
#define IMG 256
static constexpr int CDIM = 192;

typedef __attribute__((ext_vector_type(8))) short short8;
typedef __attribute__((ext_vector_type(4))) short s16x4;
typedef __attribute__((ext_vector_type(4))) float f32x4;
typedef __attribute__((ext_vector_type(2))) float f32x2;

static __device__ __forceinline__ float b2f(unsigned short u) {
    union { unsigned u; float f; } t; t.u = ((unsigned)u) << 16; return t.f;
}
static __device__ __forceinline__ unsigned short f2bu(float f) {
    __hip_bfloat16 h = __float2bfloat16(f);
    return *reinterpret_cast<unsigned short*>(&h);
}

// ---------------- pack weights fp32 -> bf16 ---------------------------------
__global__ void pack_weights(const float* __restrict__ wq,
                             const float* __restrict__ wkv,
                             const float* __restrict__ wp,
                             __hip_bfloat16* __restrict__ Wqkv,
                             __hip_bfloat16* __restrict__ Wp) {
    int i = blockIdx.x * 256 + threadIdx.x;
    if (i < 36864) Wqkv[i] = __float2bfloat16(wq[i]);
    else if (i < 110592) Wqkv[i] = __float2bfloat16(wkv[i - 36864]);
    else if (i < 147456) Wp[i - 110592] = __float2bfloat16(wp[i - 110592]);
}

// ---------------- transpose + convert: x[c][p] f32 -> xT[p][c] bf16 ---------
__global__ void transpose_cvt(const float* __restrict__ x,
                              __hip_bfloat16* __restrict__ xT) {
    __shared__ float tile[32][33];
    const int p0 = blockIdx.x * 32, c0 = blockIdx.y * 32;
    const int tx = threadIdx.x & 31, ty = threadIdx.x >> 5;
#pragma unroll
    for (int r = 0; r < 4; r++)
        tile[ty + r * 8][tx] = x[(size_t)(c0 + ty + r * 8) * HW + p0 + tx];
    __syncthreads();
    const int pl = threadIdx.x >> 3, cl = (threadIdx.x & 7) * 4;
    union { unsigned short h[4]; unsigned long long u; } ob;
#pragma unroll
    for (int e = 0; e < 4; e++) ob.h[e] = f2bu(tile[cl + e][pl]);
    *(unsigned long long*)(xT + (size_t)(p0 + pl) * 192 + c0 + cl) = ob.u;
}

// ---------------- MFMA GEMM, BN=64 (6 blocks/CU): Y = A * Bt^T, bf16 out ----
__global__ void gemm_bf16(const __hip_bfloat16* __restrict__ A,
                          const __hip_bfloat16* __restrict__ Bt,
                          __hip_bfloat16* __restrict__ Y) {
    __shared__ short Bs[64][200];
    const int tid = threadIdx.x;
    const int wid = tid >> 6, lane = tid & 63;
    const int mBase = blockIdx.x * 64, nBase = blockIdx.y * 64;

#pragma unroll
    for (int l = 0; l < 6; l++) {
        int ch = tid + l * 256;
        int row = ch / 24, cc = ch % 24;
        short8 v = *(const short8*)(Bt + (size_t)(nBase + row) * 192 + cc * 8);
        *(short8*)&Bs[row][cc * 8] = v;
    }
    __syncthreads();

    const int lr = lane & 15, lg = lane >> 4;
    const __hip_bfloat16* Ab = A + (size_t)(mBase + wid * 16 + lr) * 192 + lg * 8;
    f32x4 acc[4];
#pragma unroll
    for (int f = 0; f < 4; f++) acc[f] = (f32x4){0.f, 0.f, 0.f, 0.f};

#pragma unroll
    for (int ks = 0; ks < 6; ks++) {
        short8 af = *(const short8*)(Ab + ks * 32);
#pragma unroll
        for (int f = 0; f < 4; f++) {
            short8 bfr = *(const short8*)&Bs[f * 16 + lr][ks * 32 + lg * 8];
            acc[f] = __builtin_amdgcn_mfma_f32_16x16x32_bf16(af, bfr, acc[f], 0, 0, 0);
        }
    }

    const int mrow = mBase + wid * 16 + lg * 4;
#pragma unroll
    for (int f = 0; f < 4; f++) {
        int n = nBase + f * 16 + lr;
#pragma unroll
        for (int r = 0; r < 4; r++)
            Y[(size_t)(mrow + r) * HW + n] = __float2bfloat16(acc[f][r]);
    }
}

// ---------------- Depthwise 7x7 v5: bf16 LDS, f32x2 packed accumulate -------
__global__ __launch_bounds__(256) void dwconv7_v5(
    const __hip_bfloat16* __restrict__ in,
    const float* __restrict__ wdw,
    const float* __restrict__ bias,
    __hip_bfloat16* __restrict__ out) {
    __shared__ unsigned short tile[70][136];   // 19,040 B
    const int c = blockIdx.y;
    const int x0 = (blockIdx.x & 1) * 128;
    const int y0 = (blockIdx.x >> 1) * 64;
    const __hip_bfloat16* src = in + (size_t)c * HW;

    float w49[49];
#pragma unroll
    for (int i = 0; i < 49; i++) w49[i] = wdw[c * 49 + i];   // uniform -> SGPR
    const float bval = bias[c];

#pragma unroll
    for (int l = 0; l < 5; l++) {
        int idx = threadIdx.x + l * 256;
        if (idx < 70 * 17) {
            int r = idx / 17, cs = idx - r * 17;
            int gy = y0 + r - 3;
            int gxb = x0 + cs * 8 - 3;
            if ((unsigned)gy < IMG && gxb >= 0 && gxb + 8 <= IMG) {
                *(short8*)&tile[r][cs * 8] =
                    *(const short8*)(src + gy * IMG + gxb);
            } else {
#pragma unroll
                for (int e = 0; e < 8; e++) {
                    int gx = gxb + e;
                    unsigned short val = 0;
                    if ((unsigned)gy < IMG && (unsigned)gx < IMG)
                        val = *(const unsigned short*)(src + gy * IMG + gx);
                    tile[r][cs * 8 + e] = val;
                }
            }
        }
    }
    __syncthreads();

    const int tx4 = (threadIdx.x & 31) * 4;
    const int gy8 = (threadIdx.x >> 5) * 8;
    f32x2 acc2[8][2];
#pragma unroll
    for (int j = 0; j < 8; j++) {
        acc2[j][0] = (f32x2){bval, bval};
        acc2[j][1] = (f32x2){bval, bval};
    }

#pragma unroll
    for (int rr = 0; rr < 14; rr++) {
        const unsigned short* rowp = &tile[gy8 + rr][tx4];
        s16x4 a0 = *(const s16x4*)(rowp);
        s16x4 a1 = *(const s16x4*)(rowp + 4);
        s16x4 a2 = *(const s16x4*)(rowp + 8);
        float win[12];
#pragma unroll
        for (int e = 0; e < 4; e++) {
            win[e]     = b2f((unsigned short)a0[e]);
            win[e + 4] = b2f((unsigned short)a1[e]);
            win[e + 8] = b2f((unsigned short)a2[e]);
        }
#pragma unroll
        for (int j = 0; j < 8; j++) {
            const int ky = rr - j;
            if (ky >= 0 && ky < 7) {
#pragma unroll
                for (int kx = 0; kx < 7; kx++) {
                    const float w = w49[ky * 7 + kx];
                    const f32x2 wv = (f32x2){w, w};
                    acc2[j][0] += (f32x2){win[kx], win[kx + 1]} * wv;
                    acc2[j][1] += (f32x2){win[kx + 2], win[kx + 3]} * wv;
                }
            }
        }
    }

    __hip_bfloat16* dst = out + (size_t)c * HW + (size_t)(y0 + gy8) * IMG + x0 + tx4;
#pragma unroll
    for (int j = 0; j < 8; j++) {
        union { unsigned short h[4]; unsigned long long u; } ob;
        ob.h[0] = f2bu(acc2[j][0][0]);
        ob.h[1] = f2bu(acc2[j][0][1]);
        ob.h[2] = f2bu(acc2[j][1][0]);
        ob.h[3] = f2bu(acc2[j][1][1]);
        *(unsigned long long*)(dst + (size_t)j * IMG) = ob.u;
    }
}

// ------------- Fused dw3x3(q) + per-patch 8x8 circular conv (v3: pk-fma) ----
// f32 LDS (round-13 proven). cvt at stage time, wide f32x4 reads in loops.
__global__ __launch_bounds__(256) void circ_qfused(
    const __hip_bfloat16* __restrict__ q0,    // pre-dw q (gemm out)
    const __hip_bfloat16* __restrict__ kbuf,  // post-dw k
    const float* __restrict__ w_qdw, const float* __restrict__ b_qdw,
    __hip_bfloat16* __restrict__ sout) {
    __shared__ float qs[10][264];
    __shared__ float qP[32][68];
    __shared__ float kP[32][68];
    const int c = blockIdx.y, ph = blockIdx.x;
    const int y0 = ph * 8;
    const __hip_bfloat16* qsrc = q0 + (size_t)c * HW;
    const __hip_bfloat16* ksrc = kbuf + (size_t)c * HW;

    for (int t = threadIdx.x; t < 340; t += 256) {
        if (t < 320) {
            int r = t >> 5, ch = t & 31;
            int gy = y0 + r - 1;
            f32x4 lo = (f32x4){0.f, 0.f, 0.f, 0.f};
            f32x4 hi = (f32x4){0.f, 0.f, 0.f, 0.f};
            if ((unsigned)gy < IMG) {
                short8 v = *(const short8*)(qsrc + gy * IMG + ch * 8);
#pragma unroll
                for (int e = 0; e < 4; e++) {
                    lo[e] = b2f((unsigned short)v[e]);
                    hi[e] = b2f((unsigned short)v[4 + e]);
                }
            }
            *(f32x4*)&qs[r][4 + ch * 8] = lo;
            *(f32x4*)&qs[r][8 + ch * 8] = hi;
        } else {
            int e = t - 320;
            int r = e >> 1, s = e & 1;
            qs[r][s ? 260 : 3] = 0.f;
        }
    }
    {
        int a = threadIdx.x >> 5, ch = threadIdx.x & 31;
        short8 v = *(const short8*)(ksrc + (y0 + a) * IMG + ch * 8);
        f32x4 lo, hi;
#pragma unroll
        for (int e = 0; e < 4; e++) {
            lo[e] = b2f((unsigned short)v[e]);
            hi[e] = b2f((unsigned short)v[4 + e]);
        }
        *(f32x4*)&kP[ch][a * 8] = lo;
        *(f32x4*)&kP[ch][a * 8 + 4] = hi;
    }
    __syncthreads();

    {
        const int x = threadIdx.x;
        float w9[9];
#pragma unroll
        for (int i = 0; i < 9; i++) w9[i] = w_qdw[c * 9 + i];
        float accq[8];
#pragma unroll
        for (int j = 0; j < 8; j++) accq[j] = b_qdw[c];
#pragma unroll
        for (int kx = 0; kx < 3; kx++)
#pragma unroll
            for (int yy = 0; yy < 10; yy++) {
                float vv = qs[yy][x + kx + 3];
#pragma unroll
                for (int j = 0; j < 8; j++) {
                    int ky = yy - j;
                    if (ky >= 0 && ky < 3) accq[j] += vv * w9[ky * 3 + kx];
                }
            }
#pragma unroll
        for (int j = 0; j < 8; j++) qP[x >> 3][j * 8 + (x & 7)] = accq[j];
    }
    __syncthreads();

    const int i = threadIdx.x >> 5, pw = threadIdx.x & 31;
    float qv[8][8];
#pragma unroll
    for (int a = 0; a < 8; a++) {
        f32x4 u0 = *(const f32x4*)&qP[pw][a * 8];
        f32x4 u1 = *(const f32x4*)&qP[pw][a * 8 + 4];
        qv[a][0] = u0[0]; qv[a][1] = u0[1]; qv[a][2] = u0[2]; qv[a][3] = u0[3];
        qv[a][4] = u1[0]; qv[a][5] = u1[1]; qv[a][6] = u1[2]; qv[a][7] = u1[3];
    }
    f32x2 acc2[4];
#pragma unroll
    for (int j2 = 0; j2 < 4; j2++) acc2[j2] = (f32x2){0.f, 0.f};

#pragma unroll
    for (int a = 0; a < 8; a++) {
        const int r = (i - a + 8) & 7;
        f32x4 k0v = *(const f32x4*)&kP[pw][r * 8];
        f32x4 k1v = *(const f32x4*)&kP[pw][r * 8 + 4];
        const float kr[8] = {k0v[0], k0v[1], k0v[2], k0v[3],
                             k1v[0], k1v[1], k1v[2], k1v[3]};
        const f32x2 krE[4] = {(f32x2){kr[0], kr[1]}, (f32x2){kr[2], kr[3]},
                              (f32x2){kr[4], kr[5]}, (f32x2){kr[6], kr[7]}};
        const f32x2 krS[4] = {(f32x2){kr[1], kr[2]}, (f32x2){kr[3], kr[4]},
                              (f32x2){kr[5], kr[6]}, (f32x2){kr[7], kr[0]}};
#pragma unroll
        for (int b = 0; b < 8; b += 2) {
            const float qe = qv[a][b];
            const float qo = qv[a][b + 1];
#pragma unroll
            for (int j2 = 0; j2 < 4; j2++) {
                const int re = (2 * j2 - b + 8) & 7;
                acc2[j2] += (f32x2){qe, qe} * krE[re >> 1];
                const int ro = (2 * j2 - b - 1 + 16) & 7;
                acc2[j2] += (f32x2){qo, qo} * krS[(ro - 1) >> 1];
            }
        }
    }
    union { unsigned short h[8]; short8 s8; } ob;
#pragma unroll
    for (int j = 0; j < 8; j++) ob.h[j] = f2bu(acc2[j >> 1][j & 1]);
    *(short8*)(sout + (size_t)c * HW + (size_t)(y0 + i) * IMG + pw * 8) = ob.s8;
}

// ------------- Fused: LN(ch)+affine, *v, proj GEMM + bias (px-tile 64) ------
// LDS ~28 KB -> 5 blocks/CU. Stats split 4-way over channels.
__global__ __launch_bounds__(256) void gemm_proj_ln(
    const __hip_bfloat16* __restrict__ Wp,
    const __hip_bfloat16* __restrict__ s,
    const __hip_bfloat16* __restrict__ v,
    const float* __restrict__ ln_w, const float* __restrict__ ln_b,
    const float* __restrict__ bias,
    float* __restrict__ Y) {
    __shared__ short Bs[64][200];
    __shared__ float red[4][2][64];
    __shared__ float muA[64], rsA[64];
    const int tid = threadIdx.x;
    const int p0 = blockIdx.x * 64;
    const int px = tid & 63, h = tid >> 6;
    const unsigned short* sp = (const unsigned short*)s;

    float sum = 0.f, sq = 0.f;
#pragma unroll 4
    for (int l = 0; l < 24; l++) {
        int c = h * 48 + l * 2;
        unsigned short ua = sp[(size_t)c * HW + p0 + px];
        unsigned short ub = sp[(size_t)(c + 1) * HW + p0 + px];
        float a = b2f(ua), b = b2f(ub);
        sum += a + b;
        sq += a * a + b * b;
        *(unsigned*)&Bs[px][c] = (unsigned)ua | ((unsigned)ub << 16);
    }
    red[h][0][px] = sum;
    red[h][1][px] = sq;
    __syncthreads();
    if (tid < 64) {
        float sm = red[0][0][tid] + red[1][0][tid] + red[2][0][tid] + red[3][0][tid];
        float sQ = red[0][1][tid] + red[1][1][tid] + red[2][1][tid] + red[3][1][tid];
        float mu = sm * (1.f / 192.f);
        float var = sQ * (1.f / 192.f) - mu * mu;
        muA[tid] = mu;
        rsA[tid] = rsqrtf(var + 1e-5f);
    }
    __syncthreads();

    const float mu = muA[px], rs = rsA[px];
#pragma unroll 4
    for (int l = 0; l < 24; l++) {
        int c = h * 48 + l * 2;
        unsigned pr = *(unsigned*)&Bs[px][c];
        float a = b2f((unsigned short)pr);
        float b = b2f((unsigned short)(pr >> 16));
        float va = b2f(*(const unsigned short*)(v + (size_t)c * HW + p0 + px));
        float vb = b2f(*(const unsigned short*)(v + (size_t)(c + 1) * HW + p0 + px));
        a = ((a - mu) * rs * ln_w[c] + ln_b[c]) * va;
        b = ((b - mu) * rs * ln_w[c + 1] + ln_b[c + 1]) * vb;
        *(unsigned*)&Bs[px][c] = (unsigned)f2bu(a) | ((unsigned)f2bu(b) << 16);
    }
    __syncthreads();

    const int wid = tid >> 6, lane = tid & 63;
    const int lr = lane & 15, lg = lane >> 4;
    f32x4 acc[3][4];
#pragma unroll
    for (int mf = 0; mf < 3; mf++)
#pragma unroll
        for (int f = 0; f < 4; f++) acc[mf][f] = (f32x4){0.f, 0.f, 0.f, 0.f};

#pragma unroll
    for (int ks = 0; ks < 6; ks++) {
        short8 bfr[4];
#pragma unroll
        for (int f = 0; f < 4; f++)
            bfr[f] = *(const short8*)&Bs[f * 16 + lr][ks * 32 + lg * 8];
#pragma unroll
        for (int mf = 0; mf < 3; mf++) {
            int mrow = wid * 48 + mf * 16 + lr;
            short8 af = *(const short8*)(Wp + (size_t)mrow * 192 + ks * 32 + lg * 8);
#pragma unroll
            for (int f = 0; f < 4; f++)
                acc[mf][f] = __builtin_amdgcn_mfma_f32_16x16x32_bf16(af, bfr[f], acc[mf][f], 0, 0, 0);
        }
    }

#pragma unroll
    for (int mf = 0; mf < 3; mf++) {
        int m0 = wid * 48 + mf * 16 + lg * 4;
#pragma unroll
        for (int f = 0; f < 4; f++) {
            int n = p0 + f * 16 + lr;
#pragma unroll
            for (int r = 0; r < 4; r++)
                Y[(size_t)(m0 + r) * HW + n] = acc[mf][f][r] + bias[m0 + r];
        }
    }
}

extern "C" void kernel_launch(void* const* d_in, const int* in_sizes, int n_in,
                              void* d_out, int out_size, void* d_ws, size_t ws_size,
                              hipStream_t stream) {
    const float* x      = (const float*)d_in[0];
    const float* wq     = (const float*)d_in[1];
    const float* w_qdw  = (const float*)d_in[2];
    const float* b_qdw  = (const float*)d_in[3];
    const float* wkv    = (const float*)d_in[4];
    const float* w_kvdw = (const float*)d_in[5];
    const float* b_kvdw = (const float*)d_in[6];
    const float* ln_w   = (const float*)d_in[7];
    const float* ln_b   = (const float*)d_in[8];
    const float* w_proj = (const float*)d_in[9];
    const float* b_proj = (const float*)d_in[10];
    float* out = (float*)d_out;
    char* ws = (char*)d_ws;

    // ws map (bytes), ~176.5 MB — round-9 proven layout.
    __hip_bfloat16* qkv0  = (__hip_bfloat16*)(ws + 0);           // [576*HW]
    __hip_bfloat16* kvbuf = (__hip_bfloat16*)(ws + 75497472ull); // [384*HW] k|v
    __hip_bfloat16* sbuf  = (__hip_bfloat16*)(ws + 125829120ull);// [192*HW]
    __hip_bfloat16* xT    = (__hip_bfloat16*)(ws + 150994944ull);// [HW*192]
    __hip_bfloat16* Wqkv  = (__hip_bfloat16*)(ws + 176160768ull);// [576*192]
    __hip_bfloat16* Wp    = Wqkv + 110592;                       // [192*192]

    pack_weights<<<576, 256, 0, stream>>>(wq, wkv, w_proj, Wqkv, Wp);

    for (int b = 0; b < 4; b++) {
        const float* xb = x + (size_t)b * CDIM * HW;
        transpose_cvt<<<dim3(HW / 32, 6), 256, 0, stream>>>(xb, xT);
        // fused q+kv 1x1 conv -> bf16 (q rows 0..191, k 192..383, v 384..575)
        gemm_bf16<<<dim3(9, HW / 64), 256, 0, stream>>>(Wqkv, xT, qkv0);
        // depthwise 7x7 over k AND v (384 ch), packed-f32 v5
        dwconv7_v5<<<dim3(8, 384), 256, 0, stream>>>(qkv0 + (size_t)192 * HW,
                                                     w_kvdw, b_kvdw, kvbuf);
        // fused dw3x3(q) + per-patch circular conv (f32-LDS pk-fma v3) -> sbuf
        circ_qfused<<<dim3(32, 192), 256, 0, stream>>>(qkv0, kvbuf,
                                                       w_qdw, b_qdw, sbuf);
        // fused LN + *v + projection GEMM + bias (px-64) -> out
        gemm_proj_ln<<<HW / 64, 256, 0, stream>>>(Wp, sbuf,
                                                  kvbuf + (size_t)192 * HW,
                                                  ln_w, ln_b, b_proj,
                                                  out + (size_t)b * CDIM * HW);
    }
}

// Round 16
// 665.685 us; speedup vs baseline: 1.0722x; 1.0505x over previous
//
#include <hip/hip_runtime.h>
#include <hip/hip_bf16.h>

#define HW 65536
#define IMG 256
static constexpr int CDIM = 192;

typedef __attribute__((ext_vector_type(8))) short short8;
typedef __attribute__((ext_vector_type(4))) short s16x4;
typedef __attribute__((ext_vector_type(4))) float f32x4;
typedef __attribute__((ext_vector_type(2))) float f32x2;

// per-batch element strides (z within a pair = blockIdx.z)
static constexpr size_t BS_X   = (size_t)CDIM * HW;  // f32 input
static constexpr size_t BS_XT  = (size_t)HW * 192;   // bf16
static constexpr size_t BS_QKV = (size_t)576 * HW;   // bf16
static constexpr size_t BS_KV  = (size_t)384 * HW;   // bf16
static constexpr size_t BS_S   = (size_t)192 * HW;   // bf16
static constexpr size_t BS_OUT = (size_t)192 * HW;   // f32

static __device__ __forceinline__ float b2f(unsigned short u) {
    union { unsigned u; float f; } t; t.u = ((unsigned)u) << 16; return t.f;
}
static __device__ __forceinline__ unsigned short f2bu(float f) {
    __hip_bfloat16 h = __float2bfloat16(f);
    return *reinterpret_cast<unsigned short*>(&h);
}

// ---------------- pack weights fp32 -> bf16 ---------------------------------
__global__ void pack_weights(const float* __restrict__ wq,
                             const float* __restrict__ wkv,
                             const float* __restrict__ wp,
                             __hip_bfloat16* __restrict__ Wqkv,
                             __hip_bfloat16* __restrict__ Wp) {
    int i = blockIdx.x * 256 + threadIdx.x;
    if (i < 36864) Wqkv[i] = __float2bfloat16(wq[i]);
    else if (i < 110592) Wqkv[i] = __float2bfloat16(wkv[i - 36864]);
    else if (i < 147456) Wp[i - 110592] = __float2bfloat16(wp[i - 110592]);
}

// ---------------- transpose + convert: x[c][p] f32 -> xT[p][c] bf16 ---------
__global__ void transpose_cvt(const float* __restrict__ x,
                              __hip_bfloat16* __restrict__ xT) {
    __shared__ float tile[32][33];
    x  += (size_t)blockIdx.z * BS_X;
    xT += (size_t)blockIdx.z * BS_XT;
    const int p0 = blockIdx.x * 32, c0 = blockIdx.y * 32;
    const int tx = threadIdx.x & 31, ty = threadIdx.x >> 5;
#pragma unroll
    for (int r = 0; r < 4; r++)
        tile[ty + r * 8][tx] = x[(size_t)(c0 + ty + r * 8) * HW + p0 + tx];
    __syncthreads();
    const int pl = threadIdx.x >> 3, cl = (threadIdx.x & 7) * 4;
    union { unsigned short h[4]; unsigned long long u; } ob;
#pragma unroll
    for (int e = 0; e < 4; e++) ob.h[e] = f2bu(tile[cl + e][pl]);
    *(unsigned long long*)(xT + (size_t)(p0 + pl) * 192 + c0 + cl) = ob.u;
}

// ---------------- MFMA GEMM, BN=64 (6 blocks/CU): Y = A * Bt^T, bf16 out ----
__global__ void gemm_bf16(const __hip_bfloat16* __restrict__ A,
                          const __hip_bfloat16* __restrict__ Bt,
                          __hip_bfloat16* __restrict__ Y) {
    __shared__ short Bs[64][200];
    Bt += (size_t)blockIdx.z * BS_XT;
    Y  += (size_t)blockIdx.z * BS_QKV;
    const int tid = threadIdx.x;
    const int wid = tid >> 6, lane = tid & 63;
    const int mBase = blockIdx.x * 64, nBase = blockIdx.y * 64;

#pragma unroll
    for (int l = 0; l < 6; l++) {
        int ch = tid + l * 256;
        int row = ch / 24, cc = ch % 24;
        short8 v = *(const short8*)(Bt + (size_t)(nBase + row) * 192 + cc * 8);
        *(short8*)&Bs[row][cc * 8] = v;
    }
    __syncthreads();

    const int lr = lane & 15, lg = lane >> 4;
    const __hip_bfloat16* Ab = A + (size_t)(mBase + wid * 16 + lr) * 192 + lg * 8;
    f32x4 acc[4];
#pragma unroll
    for (int f = 0; f < 4; f++) acc[f] = (f32x4){0.f, 0.f, 0.f, 0.f};

#pragma unroll
    for (int ks = 0; ks < 6; ks++) {
        short8 af = *(const short8*)(Ab + ks * 32);
#pragma unroll
        for (int f = 0; f < 4; f++) {
            short8 bfr = *(const short8*)&Bs[f * 16 + lr][ks * 32 + lg * 8];
            acc[f] = __builtin_amdgcn_mfma_f32_16x16x32_bf16(af, bfr, acc[f], 0, 0, 0);
        }
    }

    const int mrow = mBase + wid * 16 + lg * 4;
#pragma unroll
    for (int f = 0; f < 4; f++) {
        int n = nBase + f * 16 + lr;
#pragma unroll
        for (int r = 0; r < 4; r++)
            Y[(size_t)(mrow + r) * HW + n] = __float2bfloat16(acc[f][r]);
    }
}

// ---------------- Depthwise 7x7 v5: bf16 LDS, f32x2 packed accumulate -------
__global__ __launch_bounds__(256) void dwconv7_v5(
    const __hip_bfloat16* __restrict__ in,
    const float* __restrict__ wdw,
    const float* __restrict__ bias,
    __hip_bfloat16* __restrict__ out) {
    __shared__ unsigned short tile[70][136];   // 19,040 B
    in  += (size_t)blockIdx.z * BS_QKV;
    out += (size_t)blockIdx.z * BS_KV;
    const int c = blockIdx.y;
    const int x0 = (blockIdx.x & 1) * 128;
    const int y0 = (blockIdx.x >> 1) * 64;
    const __hip_bfloat16* src = in + (size_t)c * HW;

    float w49[49];
#pragma unroll
    for (int i = 0; i < 49; i++) w49[i] = wdw[c * 49 + i];   // uniform -> SGPR
    const float bval = bias[c];

#pragma unroll
    for (int l = 0; l < 5; l++) {
        int idx = threadIdx.x + l * 256;
        if (idx < 70 * 17) {
            int r = idx / 17, cs = idx - r * 17;
            int gy = y0 + r - 3;
            int gxb = x0 + cs * 8 - 3;
            if ((unsigned)gy < IMG && gxb >= 0 && gxb + 8 <= IMG) {
                *(short8*)&tile[r][cs * 8] =
                    *(const short8*)(src + gy * IMG + gxb);
            } else {
#pragma unroll
                for (int e = 0; e < 8; e++) {
                    int gx = gxb + e;
                    unsigned short val = 0;
                    if ((unsigned)gy < IMG && (unsigned)gx < IMG)
                        val = *(const unsigned short*)(src + gy * IMG + gx);
                    tile[r][cs * 8 + e] = val;
                }
            }
        }
    }
    __syncthreads();

    const int tx4 = (threadIdx.x & 31) * 4;
    const int gy8 = (threadIdx.x >> 5) * 8;
    f32x2 acc2[8][2];
#pragma unroll
    for (int j = 0; j < 8; j++) {
        acc2[j][0] = (f32x2){bval, bval};
        acc2[j][1] = (f32x2){bval, bval};
    }

#pragma unroll
    for (int rr = 0; rr < 14; rr++) {
        const unsigned short* rowp = &tile[gy8 + rr][tx4];
        s16x4 a0 = *(const s16x4*)(rowp);
        s16x4 a1 = *(const s16x4*)(rowp + 4);
        s16x4 a2 = *(const s16x4*)(rowp + 8);
        float win[12];
#pragma unroll
        for (int e = 0; e < 4; e++) {
            win[e]     = b2f((unsigned short)a0[e]);
            win[e + 4] = b2f((unsigned short)a1[e]);
            win[e + 8] = b2f((unsigned short)a2[e]);
        }
#pragma unroll
        for (int j = 0; j < 8; j++) {
            const int ky = rr - j;
            if (ky >= 0 && ky < 7) {
#pragma unroll
                for (int kx = 0; kx < 7; kx++) {
                    const float w = w49[ky * 7 + kx];
                    const f32x2 wv = (f32x2){w, w};
                    acc2[j][0] += (f32x2){win[kx], win[kx + 1]} * wv;
                    acc2[j][1] += (f32x2){win[kx + 2], win[kx + 3]} * wv;
                }
            }
        }
    }

    __hip_bfloat16* dst = out + (size_t)c * HW + (size_t)(y0 + gy8) * IMG + x0 + tx4;
#pragma unroll
    for (int j = 0; j < 8; j++) {
        union { unsigned short h[4]; unsigned long long u; } ob;
        ob.h[0] = f2bu(acc2[j][0][0]);
        ob.h[1] = f2bu(acc2[j][0][1]);
        ob.h[2] = f2bu(acc2[j][1][0]);
        ob.h[3] = f2bu(acc2[j][1][1]);
        *(unsigned long long*)(dst + (size_t)j * IMG) = ob.u;
    }
}

// ------------- Fused dw3x3(q) + per-patch 8x8 circular conv (v3: pk-fma) ----
__global__ __launch_bounds__(256) void circ_qfused(
    const __hip_bfloat16* __restrict__ q0,    // pre-dw q (gemm out)
    const __hip_bfloat16* __restrict__ kbuf,  // post-dw k
    const float* __restrict__ w_qdw, const float* __restrict__ b_qdw,
    __hip_bfloat16* __restrict__ sout) {
    __shared__ float qs[10][264];
    __shared__ float qP[32][68];
    __shared__ float kP[32][68];
    q0   += (size_t)blockIdx.z * BS_QKV;
    kbuf += (size_t)blockIdx.z * BS_KV;
    sout += (size_t)blockIdx.z * BS_S;
    const int c = blockIdx.y, ph = blockIdx.x;
    const int y0 = ph * 8;
    const __hip_bfloat16* qsrc = q0 + (size_t)c * HW;
    const __hip_bfloat16* ksrc = kbuf + (size_t)c * HW;

    for (int t = threadIdx.x; t < 340; t += 256) {
        if (t < 320) {
            int r = t >> 5, ch = t & 31;
            int gy = y0 + r - 1;
            f32x4 lo = (f32x4){0.f, 0.f, 0.f, 0.f};
            f32x4 hi = (f32x4){0.f, 0.f, 0.f, 0.f};
            if ((unsigned)gy < IMG) {
                short8 v = *(const short8*)(qsrc + gy * IMG + ch * 8);
#pragma unroll
                for (int e = 0; e < 4; e++) {
                    lo[e] = b2f((unsigned short)v[e]);
                    hi[e] = b2f((unsigned short)v[4 + e]);
                }
            }
            *(f32x4*)&qs[r][4 + ch * 8] = lo;
            *(f32x4*)&qs[r][8 + ch * 8] = hi;
        } else {
            int e = t - 320;
            int r = e >> 1, s = e & 1;
            qs[r][s ? 260 : 3] = 0.f;
        }
    }
    {
        int a = threadIdx.x >> 5, ch = threadIdx.x & 31;
        short8 v = *(const short8*)(ksrc + (y0 + a) * IMG + ch * 8);
        f32x4 lo, hi;
#pragma unroll
        for (int e = 0; e < 4; e++) {
            lo[e] = b2f((unsigned short)v[e]);
            hi[e] = b2f((unsigned short)v[4 + e]);
        }
        *(f32x4*)&kP[ch][a * 8] = lo;
        *(f32x4*)&kP[ch][a * 8 + 4] = hi;
    }
    __syncthreads();

    {
        const int x = threadIdx.x;
        float w9[9];
#pragma unroll
        for (int i = 0; i < 9; i++) w9[i] = w_qdw[c * 9 + i];
        float accq[8];
#pragma unroll
        for (int j = 0; j < 8; j++) accq[j] = b_qdw[c];
#pragma unroll
        for (int kx = 0; kx < 3; kx++)
#pragma unroll
            for (int yy = 0; yy < 10; yy++) {
                float vv = qs[yy][x + kx + 3];
#pragma unroll
                for (int j = 0; j < 8; j++) {
                    int ky = yy - j;
                    if (ky >= 0 && ky < 3) accq[j] += vv * w9[ky * 3 + kx];
                }
            }
#pragma unroll
        for (int j = 0; j < 8; j++) qP[x >> 3][j * 8 + (x & 7)] = accq[j];
    }
    __syncthreads();

    const int i = threadIdx.x >> 5, pw = threadIdx.x & 31;
    float qv[8][8];
#pragma unroll
    for (int a = 0; a < 8; a++) {
        f32x4 u0 = *(const f32x4*)&qP[pw][a * 8];
        f32x4 u1 = *(const f32x4*)&qP[pw][a * 8 + 4];
        qv[a][0] = u0[0]; qv[a][1] = u0[1]; qv[a][2] = u0[2]; qv[a][3] = u0[3];
        qv[a][4] = u1[0]; qv[a][5] = u1[1]; qv[a][6] = u1[2]; qv[a][7] = u1[3];
    }
    f32x2 acc2[4];
#pragma unroll
    for (int j2 = 0; j2 < 4; j2++) acc2[j2] = (f32x2){0.f, 0.f};

#pragma unroll
    for (int a = 0; a < 8; a++) {
        const int r = (i - a + 8) & 7;
        f32x4 k0v = *(const f32x4*)&kP[pw][r * 8];
        f32x4 k1v = *(const f32x4*)&kP[pw][r * 8 + 4];
        const float kr[8] = {k0v[0], k0v[1], k0v[2], k0v[3],
                             k1v[0], k1v[1], k1v[2], k1v[3]};
        const f32x2 krE[4] = {(f32x2){kr[0], kr[1]}, (f32x2){kr[2], kr[3]},
                              (f32x2){kr[4], kr[5]}, (f32x2){kr[6], kr[7]}};
        const f32x2 krS[4] = {(f32x2){kr[1], kr[2]}, (f32x2){kr[3], kr[4]},
                              (f32x2){kr[5], kr[6]}, (f32x2){kr[7], kr[0]}};
#pragma unroll
        for (int b = 0; b < 8; b += 2) {
            const float qe = qv[a][b];
            const float qo = qv[a][b + 1];
#pragma unroll
            for (int j2 = 0; j2 < 4; j2++) {
                const int re = (2 * j2 - b + 8) & 7;
                acc2[j2] += (f32x2){qe, qe} * krE[re >> 1];
                const int ro = (2 * j2 - b - 1 + 16) & 7;
                acc2[j2] += (f32x2){qo, qo} * krS[(ro - 1) >> 1];
            }
        }
    }
    union { unsigned short h[8]; short8 s8; } ob;
#pragma unroll
    for (int j = 0; j < 8; j++) ob.h[j] = f2bu(acc2[j >> 1][j & 1]);
    *(short8*)(sout + (size_t)c * HW + (size_t)(y0 + i) * IMG + pw * 8) = ob.s8;
}

// ------------- Fused: LN(ch)+affine, *v, proj GEMM + bias (px-128, proven) --
__global__ __launch_bounds__(256, 2) void gemm_proj_ln(
    const __hip_bfloat16* __restrict__ Wp,
    const __hip_bfloat16* __restrict__ s,
    const __hip_bfloat16* __restrict__ v,
    const float* __restrict__ ln_w, const float* __restrict__ ln_b,
    const float* __restrict__ bias,
    float* __restrict__ Y) {
    __shared__ short Bs[128][200];
    __shared__ float red[2][2][128];
    __shared__ float muA[128], rsA[128];
    s += (size_t)blockIdx.z * BS_S;
    v += (size_t)blockIdx.z * BS_KV;
    Y += (size_t)blockIdx.z * BS_OUT;
    const int tid = threadIdx.x;
    const int p0 = blockIdx.x * 128;
    const int px = tid & 127, h = tid >> 7;
    const unsigned short* sp = (const unsigned short*)s;

    float sum = 0.f, sq = 0.f;
#pragma unroll 4
    for (int l = 0; l < 48; l++) {
        int c = h * 96 + l * 2;
        unsigned short ua = sp[(size_t)c * HW + p0 + px];
        unsigned short ub = sp[(size_t)(c + 1) * HW + p0 + px];
        float a = b2f(ua), b = b2f(ub);
        sum += a + b;
        sq += a * a + b * b;
        *(unsigned*)&Bs[px][c] = (unsigned)ua | ((unsigned)ub << 16);
    }
    red[h][0][px] = sum;
    red[h][1][px] = sq;
    __syncthreads();
    if (tid < 128) {
        float sm = red[0][0][tid] + red[1][0][tid];
        float sQ = red[0][1][tid] + red[1][1][tid];
        float mu = sm * (1.f / 192.f);
        float var = sQ * (1.f / 192.f) - mu * mu;
        muA[tid] = mu;
        rsA[tid] = rsqrtf(var + 1e-5f);
    }
    __syncthreads();

    const float mu = muA[px], rs = rsA[px];
#pragma unroll 4
    for (int l = 0; l < 48; l++) {
        int c = h * 96 + l * 2;
        unsigned pr = *(unsigned*)&Bs[px][c];
        float a = b2f((unsigned short)pr);
        float b = b2f((unsigned short)(pr >> 16));
        float va = b2f(*(const unsigned short*)(v + (size_t)c * HW + p0 + px));
        float vb = b2f(*(const unsigned short*)(v + (size_t)(c + 1) * HW + p0 + px));
        a = ((a - mu) * rs * ln_w[c] + ln_b[c]) * va;
        b = ((b - mu) * rs * ln_w[c + 1] + ln_b[c + 1]) * vb;
        *(unsigned*)&Bs[px][c] = (unsigned)f2bu(a) | ((unsigned)f2bu(b) << 16);
    }
    __syncthreads();

    const int wid = tid >> 6, lane = tid & 63;
    const int lr = lane & 15, lg = lane >> 4;
    f32x4 acc[3][8];
#pragma unroll
    for (int mf = 0; mf < 3; mf++)
#pragma unroll
        for (int f = 0; f < 8; f++) acc[mf][f] = (f32x4){0.f, 0.f, 0.f, 0.f};

#pragma unroll
    for (int ks = 0; ks < 6; ks++) {
        short8 bfr[8];
#pragma unroll
        for (int f = 0; f < 8; f++)
            bfr[f] = *(const short8*)&Bs[f * 16 + lr][ks * 32 + lg * 8];
#pragma unroll
        for (int mf = 0; mf < 3; mf++) {
            int mrow = wid * 48 + mf * 16 + lr;
            short8 af = *(const short8*)(Wp + (size_t)mrow * 192 + ks * 32 + lg * 8);
#pragma unroll
            for (int f = 0; f < 8; f++)
                acc[mf][f] = __builtin_amdgcn_mfma_f32_16x16x32_bf16(af, bfr[f], acc[mf][f], 0, 0, 0);
        }
    }

#pragma unroll
    for (int mf = 0; mf < 3; mf++) {
        int m0 = wid * 48 + mf * 16 + lg * 4;
#pragma unroll
        for (int f = 0; f < 8; f++) {
            int n = p0 + f * 16 + lr;
#pragma unroll
            for (int r = 0; r < 4; r++)
                Y[(size_t)(m0 + r) * HW + n] = acc[mf][f][r] + bias[m0 + r];
        }
    }
}

extern "C" void kernel_launch(void* const* d_in, const int* in_sizes, int n_in,
                              void* d_out, int out_size, void* d_ws, size_t ws_size,
                              hipStream_t stream) {
    const float* x      = (const float*)d_in[0];
    const float* wq     = (const float*)d_in[1];
    const float* w_qdw  = (const float*)d_in[2];
    const float* b_qdw  = (const float*)d_in[3];
    const float* wkv    = (const float*)d_in[4];
    const float* w_kvdw = (const float*)d_in[5];
    const float* b_kvdw = (const float*)d_in[6];
    const float* ln_w   = (const float*)d_in[7];
    const float* ln_b   = (const float*)d_in[8];
    const float* w_proj = (const float*)d_in[9];
    const float* b_proj = (const float*)d_in[10];
    float* out = (float*)d_out;
    char* ws = (char*)d_ws;

    // Pair-batched (z=2) ws layout, ~353 MB (ws_size >= 604 MB proven r7):
    //   qkv0  [2][576*HW] bf16 @ 0            (150,994,944 B)
    //   kvbuf [2][384*HW] bf16 @ 150,994,944  (100,663,296 B)
    //   sbuf  [2][192*HW] bf16 @ 251,658,240  ( 50,331,648 B)
    //   xT    [2][HW*192] bf16 @ 301,989,888  ( 50,331,648 B)
    //   Wqkv/Wp bf16          @ 352,321,536
    __hip_bfloat16* qkv0  = (__hip_bfloat16*)(ws + 0);
    __hip_bfloat16* kvbuf = (__hip_bfloat16*)(ws + 150994944ull);
    __hip_bfloat16* sbuf  = (__hip_bfloat16*)(ws + 251658240ull);
    __hip_bfloat16* xT    = (__hip_bfloat16*)(ws + 301989888ull);
    __hip_bfloat16* Wqkv  = (__hip_bfloat16*)(ws + 352321536ull);
    __hip_bfloat16* Wp    = Wqkv + 110592;

    pack_weights<<<576, 256, 0, stream>>>(wq, wkv, w_proj, Wqkv, Wp);

    for (int p = 0; p < 2; p++) {
        const float* xp = x + (size_t)(p * 2) * BS_X;
        float* outp = out + (size_t)(p * 2) * BS_OUT;
        transpose_cvt<<<dim3(HW / 32, 6, 2), 256, 0, stream>>>(xp, xT);
        gemm_bf16<<<dim3(9, HW / 64, 2), 256, 0, stream>>>(Wqkv, xT, qkv0);
        dwconv7_v5<<<dim3(8, 384, 2), 256, 0, stream>>>(qkv0 + (size_t)192 * HW,
                                                        w_kvdw, b_kvdw, kvbuf);
        circ_qfused<<<dim3(32, 192, 2), 256, 0, stream>>>(qkv0, kvbuf,
                                                          w_qdw, b_qdw, sbuf);
        gemm_proj_ln<<<dim3(HW / 128, 1, 2), 256, 0, stream>>>(
            Wp, sbuf, kvbuf + (size_t)192 * HW, ln_w, ln_b, b_proj, outp);
    }
}